// Round 1
// baseline (1080.852 us; speedup 1.0000x reference)
//
#include <hip/hip_runtime.h>

#define NN 50000
#define NE 600000
#define HD 128

typedef __attribute__((ext_vector_type(8))) short short8;
typedef __attribute__((ext_vector_type(4))) float floatx4;

__device__ __forceinline__ unsigned short f2bf(float f) {
  unsigned int u = __builtin_bit_cast(unsigned int, f);
  u += 0x7FFFu + ((u >> 16) & 1u);
  return (unsigned short)(u >> 16);
}

// Pack W[K][128] f32 row-major -> bf16 in MFMA B-fragment order:
// wp[((k0*8+n0)*64 + lane)*8 + j] = W[k0*32 + (lane>>4)*8 + j][n0*16 + (lane&15)]
__global__ void pack_w(const float* __restrict__ w, unsigned short* __restrict__ wp,
                       int total) {
  int p = blockIdx.x * blockDim.x + threadIdx.x;
  if (p >= total) return;
  int j = p & 7, lane = (p >> 3) & 63, t = p >> 9;
  int n0 = t & 7, k0 = t >> 3;
  int k = k0 * 32 + (lane >> 4) * 8 + j;
  int n = n0 * 16 + (lane & 15);
  wp[p] = f2bf(w[k * HD + n]);
}

// One GEMM layer for a wave's 16 rows x 128 cols.
// a_base: LDS base of this wave's row 0 (bf16), a_stride in elements.
// wp: packed weights. acc[8] tiles of 16x16.
template <int KSTEPS>
__device__ __forceinline__ void gemm_tile(const unsigned short* a_base, int a_stride,
                                          const unsigned short* __restrict__ wp,
                                          int lane, floatx4* acc) {
  int quad = lane >> 4, l16 = lane & 15;
  for (int k0 = 0; k0 < KSTEPS; ++k0) {
    short8 a = *(const short8*)(a_base + l16 * a_stride + k0 * 32 + quad * 8);
    const unsigned short* w = wp + k0 * 4096 + lane * 8;
#pragma unroll
    for (int n0 = 0; n0 < 8; ++n0) {
      short8 b = *(const short8*)(w + n0 * 512);
      acc[n0] = __builtin_amdgcn_mfma_f32_16x16x32_bf16(a, b, acc[n0], 0, 0, 0);
    }
  }
}

__device__ __forceinline__ void store_relu_bf16(const floatx4* acc,
                                                const float* __restrict__ bias,
                                                unsigned short* out_base, int stride,
                                                int lane) {
  int quad = lane >> 4, l16 = lane & 15;
#pragma unroll
  for (int n0 = 0; n0 < 8; ++n0) {
    float bv = bias[n0 * 16 + l16];
#pragma unroll
    for (int r = 0; r < 4; ++r) {
      float v = acc[n0][r] + bv;
      v = v > 0.f ? v : 0.f;
      out_base[(quad * 4 + r) * stride + n0 * 16 + l16] = f2bf(v);
    }
  }
}

#define SIN 392  // 384 + 8 pad (row stride shifts 4 banks -> conflict-free b128)
#define SH 136   // 128 + 8 pad
#define SNI 264  // 256 + 8 pad

__global__ __launch_bounds__(256) void edge_kernel(
    const float* __restrict__ x, const float* __restrict__ e,
    const int* __restrict__ idx, const unsigned short* __restrict__ w0p,
    const float* __restrict__ b0, const unsigned short* __restrict__ w1p,
    const float* __restrict__ b1, const unsigned short* __restrict__ w2p,
    const float* __restrict__ b2, const float* __restrict__ g,
    const float* __restrict__ bg, float* __restrict__ e_out,
    float* __restrict__ agg) {
  __shared__ __align__(16) unsigned short lin[64 * SIN];  // 50176 B (also h2 reuse)
  __shared__ __align__(16) unsigned short lh[64 * SH];    // 17408 B
  __shared__ int sdst[64];

  int wave = threadIdx.x >> 6, lane = threadIdx.x & 63;
  int quad = lane >> 4, l16 = lane & 15;
  int ebase = blockIdx.x * 64;

  // Stage: wave w gathers+converts its own rows w*16..w*16+15. No barriers:
  // each wave only ever touches its own LDS rows.
  for (int r = wave * 16; r < wave * 16 + 16; ++r) {
    int ei = ebase + r;
    int s = idx[ei], d = idx[NE + ei];
    if (lane == 0) sdst[r] = d;
    const float* xd = x + (size_t)d * HD;
    const float* xs = x + (size_t)s * HD;
    const float* ee = e + (size_t)ei * HD;
    unsigned short* row = lin + r * SIN;
    row[lane] = f2bf(xd[lane]);
    row[64 + lane] = f2bf(xd[64 + lane]);
    row[128 + lane] = f2bf(xs[lane]);
    row[192 + lane] = f2bf(xs[64 + lane]);
    row[256 + lane] = f2bf(ee[lane]);
    row[320 + lane] = f2bf(ee[64 + lane]);
  }

  floatx4 acc[8];
  floatx4 z = {0.f, 0.f, 0.f, 0.f};

  // layer0: [16,384] @ [384,128] + relu -> lh
#pragma unroll
  for (int t = 0; t < 8; ++t) acc[t] = z;
  gemm_tile<12>(lin + wave * 16 * SIN, SIN, w0p, lane, acc);
  store_relu_bf16(acc, b0, lh + wave * 16 * SH, SH, lane);

  // layer1: [16,128] @ [128,128] + relu -> h2 (reuse this wave's lin region)
  unsigned short* h2 = lin + wave * 16 * SIN;
#pragma unroll
  for (int t = 0; t < 8; ++t) acc[t] = z;
  gemm_tile<4>(lh + wave * 16 * SH, SH, w1p, lane, acc);
  store_relu_bf16(acc, b1, h2, SH, lane);

  // layer2: [16,128] @ [128,128] (no relu), keep in regs
#pragma unroll
  for (int t = 0; t < 8; ++t) acc[t] = z;
  gemm_tile<4>(h2, SH, w2p, lane, acc);

  // bias + LayerNorm (rows r_local = quad*4+r, cols n0*16+l16)
  float h3[8][4];
#pragma unroll
  for (int n0 = 0; n0 < 8; ++n0) {
    float bv = b2[n0 * 16 + l16];
#pragma unroll
    for (int r = 0; r < 4; ++r) h3[n0][r] = acc[n0][r] + bv;
  }
  float s1[4] = {0.f, 0.f, 0.f, 0.f}, s2[4] = {0.f, 0.f, 0.f, 0.f};
#pragma unroll
  for (int n0 = 0; n0 < 8; ++n0)
#pragma unroll
    for (int r = 0; r < 4; ++r) {
      s1[r] += h3[n0][r];
      s2[r] += h3[n0][r] * h3[n0][r];
    }
#pragma unroll
  for (int m = 1; m < 16; m <<= 1) {
#pragma unroll
    for (int r = 0; r < 4; ++r) {
      s1[r] += __shfl_xor(s1[r], m, 64);
      s2[r] += __shfl_xor(s2[r], m, 64);
    }
  }
  float mu[4], rs[4];
#pragma unroll
  for (int r = 0; r < 4; ++r) {
    mu[r] = s1[r] * (1.f / 128.f);
    float var = s2[r] * (1.f / 128.f) - mu[r] * mu[r];
    rs[r] = rsqrtf(var + 1e-5f);
  }
  // write e_new + scatter-add into agg[dst]
#pragma unroll
  for (int n0 = 0; n0 < 8; ++n0) {
    int col = n0 * 16 + l16;
    float gv = g[col], bv = bg[col];
#pragma unroll
    for (int r = 0; r < 4; ++r) {
      int rl = wave * 16 + quad * 4 + r;
      int ei = ebase + rl;
      float v = (h3[n0][r] - mu[r]) * rs[r] * gv + bv;
      e_out[(size_t)ei * HD + col] = v;
      atomicAdd(&agg[(size_t)sdst[rl] * HD + col], v);
    }
  }
}

__global__ __launch_bounds__(256) void node_kernel(
    const float* __restrict__ x, const float* __restrict__ agg,
    const unsigned short* __restrict__ w0p, const float* __restrict__ b0,
    const unsigned short* __restrict__ w1p, const float* __restrict__ b1,
    const unsigned short* __restrict__ w2p, const float* __restrict__ b2,
    const float* __restrict__ g, const float* __restrict__ bg,
    float* __restrict__ x_out) {
  __shared__ __align__(16) unsigned short lin[64 * SNI];  // 33792 B (also h2 reuse)
  __shared__ __align__(16) unsigned short lh[64 * SH];    // 17408 B

  int wave = threadIdx.x >> 6, lane = threadIdx.x & 63;
  int quad = lane >> 4, l16 = lane & 15;
  int nbase = blockIdx.x * 64;

  for (int r = wave * 16; r < wave * 16 + 16; ++r) {
    int ni = nbase + r;
    int nc = ni < NN ? ni : NN - 1;
    const float* xr = x + (size_t)nc * HD;
    const float* ar = agg + (size_t)nc * HD;
    unsigned short* row = lin + r * SNI;
    row[lane] = f2bf(xr[lane]);
    row[64 + lane] = f2bf(xr[64 + lane]);
    row[128 + lane] = f2bf(ar[lane]);
    row[192 + lane] = f2bf(ar[64 + lane]);
  }

  floatx4 acc[8];
  floatx4 z = {0.f, 0.f, 0.f, 0.f};

#pragma unroll
  for (int t = 0; t < 8; ++t) acc[t] = z;
  gemm_tile<8>(lin + wave * 16 * SNI, SNI, w0p, lane, acc);
  store_relu_bf16(acc, b0, lh + wave * 16 * SH, SH, lane);

  unsigned short* h2 = lin + wave * 16 * SNI;
#pragma unroll
  for (int t = 0; t < 8; ++t) acc[t] = z;
  gemm_tile<4>(lh + wave * 16 * SH, SH, w1p, lane, acc);
  store_relu_bf16(acc, b1, h2, SH, lane);

#pragma unroll
  for (int t = 0; t < 8; ++t) acc[t] = z;
  gemm_tile<4>(h2, SH, w2p, lane, acc);

  float h3[8][4];
#pragma unroll
  for (int n0 = 0; n0 < 8; ++n0) {
    float bv = b2[n0 * 16 + l16];
#pragma unroll
    for (int r = 0; r < 4; ++r) h3[n0][r] = acc[n0][r] + bv;
  }
  float s1[4] = {0.f, 0.f, 0.f, 0.f}, s2[4] = {0.f, 0.f, 0.f, 0.f};
#pragma unroll
  for (int n0 = 0; n0 < 8; ++n0)
#pragma unroll
    for (int r = 0; r < 4; ++r) {
      s1[r] += h3[n0][r];
      s2[r] += h3[n0][r] * h3[n0][r];
    }
#pragma unroll
  for (int m = 1; m < 16; m <<= 1) {
#pragma unroll
    for (int r = 0; r < 4; ++r) {
      s1[r] += __shfl_xor(s1[r], m, 64);
      s2[r] += __shfl_xor(s2[r], m, 64);
    }
  }
  float mu[4], rs[4];
#pragma unroll
  for (int r = 0; r < 4; ++r) {
    mu[r] = s1[r] * (1.f / 128.f);
    float var = s2[r] * (1.f / 128.f) - mu[r] * mu[r];
    rs[r] = rsqrtf(var + 1e-5f);
  }
#pragma unroll
  for (int n0 = 0; n0 < 8; ++n0) {
    int col = n0 * 16 + l16;
    float gv = g[col], bv = bg[col];
#pragma unroll
    for (int r = 0; r < 4; ++r) {
      int rl = wave * 16 + quad * 4 + r;
      int ni = nbase + rl;
      if (ni < NN) {
        float v = (h3[n0][r] - mu[r]) * rs[r] * gv + bv;
        x_out[(size_t)ni * HD + col] = x[(size_t)ni * HD + col] + v;
      }
    }
  }
}

extern "C" void kernel_launch(void* const* d_in, const int* in_sizes, int n_in,
                              void* d_out, int out_size, void* d_ws, size_t ws_size,
                              hipStream_t stream) {
  const float* x = (const float*)d_in[0];
  const float* e = (const float*)d_in[1];
  const int* idx = (const int*)d_in[2];
  const float* we0 = (const float*)d_in[3];
  const float* be0 = (const float*)d_in[4];
  const float* we1 = (const float*)d_in[5];
  const float* be1 = (const float*)d_in[6];
  const float* we2 = (const float*)d_in[7];
  const float* be2 = (const float*)d_in[8];
  const float* ge = (const float*)d_in[9];
  const float* bge = (const float*)d_in[10];
  const float* wn0 = (const float*)d_in[11];
  const float* bn0 = (const float*)d_in[12];
  const float* wn1 = (const float*)d_in[13];
  const float* bn1 = (const float*)d_in[14];
  const float* wn2 = (const float*)d_in[15];
  const float* bn2 = (const float*)d_in[16];
  const float* gn = (const float*)d_in[17];
  const float* bgn = (const float*)d_in[18];

  float* xout = (float*)d_out;                    // [N,128]; doubles as agg buffer
  float* eout = (float*)d_out + (size_t)NN * HD;  // [E,128]

  unsigned short* ws = (unsigned short*)d_ws;
  unsigned short* w0p = ws;                  // 384*128
  unsigned short* w1p = w0p + 384 * HD;      // 128*128
  unsigned short* w2p = w1p + HD * HD;       // 128*128
  unsigned short* wn0p = w2p + HD * HD;      // 256*128
  unsigned short* wn1p = wn0p + 256 * HD;    // 128*128
  unsigned short* wn2p = wn1p + HD * HD;     // 128*128

  hipMemsetAsync(xout, 0, (size_t)NN * HD * sizeof(float), stream);

  pack_w<<<(384 * HD + 255) / 256, 256, 0, stream>>>(we0, w0p, 384 * HD);
  pack_w<<<(HD * HD + 255) / 256, 256, 0, stream>>>(we1, w1p, HD * HD);
  pack_w<<<(HD * HD + 255) / 256, 256, 0, stream>>>(we2, w2p, HD * HD);
  pack_w<<<(256 * HD + 255) / 256, 256, 0, stream>>>(wn0, wn0p, 256 * HD);
  pack_w<<<(HD * HD + 255) / 256, 256, 0, stream>>>(wn1, wn1p, HD * HD);
  pack_w<<<(HD * HD + 255) / 256, 256, 0, stream>>>(wn2, wn2p, HD * HD);

  edge_kernel<<<NE / 64, 256, 0, stream>>>(x, e, idx, w0p, be0, w1p, be1, w2p, be2,
                                           ge, bge, eout, xout);
  node_kernel<<<(NN + 63) / 64, 256, 0, stream>>>(x, xout, wn0p, bn0, wn1p, bn1,
                                                  wn2p, bn2, gn, bgn, xout);
}